// Round 5
// baseline (188.164 us; speedup 1.0000x reference)
//
#include <hip/hip_runtime.h>

// ============================================================================
// AttentionWithSpatial: x@Wqkv -> masked/biased 4-head attention -> @Wout+b
// b=4, n=2048, dim=256, heads=4, dhead=64, scale=0.125
//
// R4 was latency-bound: 2 waves/SIMD, per-iter barrier (bias LDS dbuf) with
// full vmcnt/lgkm drain, reg-copy serialization. R5:
//  - bias read per-lane direct from global in fragment layout (int4+float4)
//    -> NO __syncthreads in the k-loop at all (waves free-running).
//  - KV-split=2 (flash-decoding): grid 1024 -> 4 blocks/CU, 16 waves/CU.
//    Partial O (fp32, unnormalized) + m,l -> ws; k_comb merges + split-writes.
//  - k-loop unrolled x2 with alternating reg buffers (no copies).
//  - XCD mapping: (b,half) per XCD -> K/V slice 1MB L2-resident.
// ============================================================================

#define B_   4
#define N_   2048
#define H_   4
#define DH_  64
#define DIMX 256
#define M_   (B_*N_)   // 8192

#define LOG2E  1.4426950408889634f
#define NEGINF (-1e30f)
#define DEFER_THR 8.0f

typedef __attribute__((ext_vector_type(8))) short short8;
typedef __attribute__((ext_vector_type(4))) float f32x4;
typedef unsigned short u16;
typedef unsigned int   u32;

#define MFMA16(a,b,c) __builtin_amdgcn_mfma_f32_16x16x32_bf16((a),(b),(c),0,0,0)

__device__ __forceinline__ u16 f2bf(float f) {
  u32 u = __builtin_bit_cast(u32, f);
  u += 0x7fffu + ((u >> 16) & 1u);   // RNE
  return (u16)(u >> 16);
}
__device__ __forceinline__ float bf2f(u16 h) {
  u32 u = ((u32)h) << 16;
  return __builtin_bit_cast(float, u);
}
__device__ __forceinline__ void split2(float f, u16* hi, u16* lo) {
  u16 h = f2bf(f);
  *hi = h;
  *lo = f2bf(f - bf2f(h));
}
__device__ __forceinline__ float bpermf(int srclane, float v) {
  return __builtin_bit_cast(float,
      __builtin_amdgcn_ds_bpermute(srclane << 2, __builtin_bit_cast(int, v)));
}
__device__ __forceinline__ u32 cvtpk(float lo, float hi) {
  u32 r;
  asm("v_cvt_pk_bf16_f32 %0, %1, %2" : "=v"(r) : "v"(lo), "v"(hi));
  return r;
}

struct u16v4 { u16 a, b, c, d; };
struct u16v8 { u16 v[8]; };

// ---------------------------------------------------------------------------
// Kernel 1: split x into hi/lo bf16 (float4 path); transpose+split Wqkv/Wout.
// ---------------------------------------------------------------------------
__global__ __launch_bounds__(256) void k_split(
    const float* __restrict__ x, const float* __restrict__ wq,
    const float* __restrict__ wo,
    u16* __restrict__ xh, u16* __restrict__ xl,
    u16* __restrict__ wqh, u16* __restrict__ wql,
    u16* __restrict__ woh, u16* __restrict__ wol)
{
  const int NX4 = (M_ * DIMX) / 4;  // 524288
  const int NWQ = 768 * 256;        // 196608
  const int NWO = 256 * 256;        // 65536
  int i = blockIdx.x * 256 + threadIdx.x;
  if (i < NX4) {
    const float4 v = ((const float4*)x)[i];
    u16v4 hv, lv;
    split2(v.x, &hv.a, &lv.a);
    split2(v.y, &hv.b, &lv.b);
    split2(v.z, &hv.c, &lv.c);
    split2(v.w, &hv.d, &lv.d);
    ((u16v4*)xh)[i] = hv;
    ((u16v4*)xl)[i] = lv;
  } else if (i < NX4 + NWQ) {
    int j = i - NX4;
    int c = j >> 8, k = j & 255;            // out layout [c][k]
    split2(wq[k * 768 + c], &wqh[j], &wql[j]);
  } else if (i < NX4 + NWQ + NWO) {
    int j = i - NX4 - NWQ;
    int c = j >> 8, k = j & 255;
    split2(wo[k * 256 + c], &woh[j], &wol[j]);
  }
}

// ---------------------------------------------------------------------------
// Kernel 2: QKV GEMM. M=8192, N=768, K=256. Block = 4 waves, 64x64 tile.
// Q pre-scaled by 0.125*log2e, split hi/lo, layout [bh][n][d].
// K fragment-major: (bh*64+kt)*2048 + (kc*2+j)*512 + lane*8 + e
// V fragment-major: (bh*64+kt)*2048 + j2*512 + lane*8 + e  (V^T fragments)
// ---------------------------------------------------------------------------
__global__ __launch_bounds__(256) void k_qkv(
    const u16* __restrict__ xh, const u16* __restrict__ xl,
    const u16* __restrict__ wh, const u16* __restrict__ wl,
    u16* __restrict__ qh, u16* __restrict__ ql,
    u16* __restrict__ kf, u16* __restrict__ vf)
{
  const int w = threadIdx.x >> 6, lane = threadIdx.x & 63;
  const int ln = lane & 15, hb = lane >> 4;
  const int arow = blockIdx.y * 64 + w * 16 + ln;
  const int colb = blockIdx.x * 64;

  f32x4 acc[4] = {};
  for (int ks = 0; ks < 8; ++ks) {
    const int k0 = ks * 32 + hb * 8;
    short8 a_h = *(const short8*)&xh[arow * 256 + k0];
    short8 a_l = *(const short8*)&xl[arow * 256 + k0];
#pragma unroll
    for (int j = 0; j < 4; ++j) {
      const int c = colb + j * 16 + ln;
      short8 b_h = *(const short8*)&wh[c * 256 + k0];
      short8 b_l = *(const short8*)&wl[c * 256 + k0];
      acc[j] = MFMA16(a_h, b_h, acc[j]);
      acc[j] = MFMA16(a_l, b_h, acc[j]);
      acc[j] = MFMA16(a_h, b_l, acc[j]);
    }
  }
  const int mbase = blockIdx.y * 64 + w * 16 + hb * 4;
#pragma unroll
  for (int j = 0; j < 4; ++j) {
    const int c = colb + j * 16 + ln;
    const int which = c >> 8;        // 0=q 1=k 2=v
    const int hd = c & 255;
    const int hh = hd >> 6, d = hd & 63;
#pragma unroll
    for (int r = 0; r < 4; ++r) {
      const int m = mbase + r;
      const int bb = m >> 11, nn = m & 2047;
      const int bh = bb * H_ + hh;
      float v = acc[j][r];
      if (which == 0) {
        const int off = (bh * N_ + nn) * DH_ + d;
        v *= (0.125f * LOG2E);                 // scale + exp2-domain fold
        split2(v, &qh[off], &ql[off]);
      } else if (which == 1) {
        const int ktile = nn >> 5, jj = (nn >> 4) & 1, lnn = nn & 15;
        const int kc = d >> 5, hbb = (d >> 3) & 3, e = d & 7;
        const int off = (bh * 64 + ktile) * 2048 + (kc * 2 + jj) * 512
                      + (hbb * 16 + lnn) * 8 + e;
        kf[off] = f2bf(v);
      } else {
        const int ktile = nn >> 5, hbb = (nn >> 3) & 3, e = nn & 7;
        const int j2 = d >> 4, lnn = d & 15;
        const int off = (bh * 64 + ktile) * 2048 + j2 * 512
                      + (hbb * 16 + lnn) * 8 + e;
        vf[off] = f2bf(v);
      }
    }
  }
}

// ---------------------------------------------------------------------------
// Kernel 3: flash attention partials. grid 1024: bid -> xcd=bid&7
// (b=xcd>>1, half=xcd&1), qt=bid>>3. 4 waves = 4 heads, NO barriers.
// Each wave: 32 kv-tiles, K/V/bias prefetched 1 tile ahead in regs,
// loop unrolled x2. Writes unnormalized O (fp32) + per-row m,l.
// ---------------------------------------------------------------------------
__global__ __launch_bounds__(256) void k_attn(
    const u16* __restrict__ qhg, const u16* __restrict__ qlg,
    const u16* __restrict__ kfg, const u16* __restrict__ vfg,
    const int* __restrict__ mask, const float* __restrict__ spat,
    float* __restrict__ Op, float* __restrict__ MP, float* __restrict__ LP)
{
  __shared__ __align__(16) u32 Pbuf[4][320];   // per-wave, stride 20 u32/row

  const int bid = blockIdx.x;
  const int xcd = bid & 7;
  const int b = xcd >> 1, half = xcd & 1;
  const int qt = bid >> 3;                 // [0,128)
  const int kt0 = half * 32;

  const int tid = threadIdx.x;
  const int w = tid >> 6, lane = tid & 63; // wave = head
  const int ln = lane & 15, hb = lane >> 4;
  const int bh = b * H_ + w;

  // ---- Q fragments (pre-scaled by 0.125*log2e), hi/lo ----
  short8 qfh[2], qfl[2];
  {
    const int base = (bh * N_ + qt * 16 + ln) * DH_;
    qfh[0] = *(const short8*)&qhg[base + hb * 8];
    qfh[1] = *(const short8*)&qhg[base + 32 + hb * 8];
    qfl[0] = *(const short8*)&qlg[base + hb * 8];
    qfl[1] = *(const short8*)&qlg[base + 32 + hb * 8];
  }

  // per-lane bias address: row q=qt*16+ln, cols kt*32 + j*16 + hb*4 + {0..3}
  const int boff = (b * N_ + qt * 16 + ln) * N_ + hb * 4;

  const u16* Kbase = kfg + (size_t)(bh * 64) * 2048;
  const u16* Vbase = vfg + (size_t)(bh * 64) * 2048;
  const int l8 = lane * 8;

  short8 ones;
#pragma unroll
  for (int i = 0; i < 8; ++i) ones[i] = (short)0x3F80;   // bf16 1.0

  f32x4 O[4] = {};
  f32x4 l_acc = {};
  float m_run = NEGINF;

  u32* Pw = &Pbuf[w][0];

  short8 Ka[4], Va[4], Kb[4], Vb[4];
  int4   bMa[2], bMb[2];
  float4 bSa[2], bSb[2];

  // ---- prologue: tile kt0 into buffer A ----
  {
    const u16* Kt = Kbase + kt0 * 2048;
    const u16* Vt = Vbase + kt0 * 2048;
#pragma unroll
    for (int i = 0; i < 4; ++i) {
      Ka[i] = *(const short8*)&Kt[i * 512 + l8];
      Va[i] = *(const short8*)&Vt[i * 512 + l8];
    }
    bMa[0] = *(const int4*)&mask[boff + kt0 * 32];
    bMa[1] = *(const int4*)&mask[boff + kt0 * 32 + 16];
    bSa[0] = *(const float4*)&spat[boff + kt0 * 32];
    bSa[1] = *(const float4*)&spat[boff + kt0 * 32 + 16];
  }

  auto body = [&](short8 (&Kc)[4], short8 (&Vc)[4],
                  short8 (&Kn)[4], short8 (&Vn)[4],
                  int4 (&bMc)[2], float4 (&bSc)[2],
                  int4 (&bMn)[2], float4 (&bSn)[2], int ktn) {
    // ---- prefetch next tile ----
    {
      const u16* Kt = Kbase + ktn * 2048;
      const u16* Vt = Vbase + ktn * 2048;
#pragma unroll
      for (int i = 0; i < 4; ++i) {
        Kn[i] = *(const short8*)&Kt[i * 512 + l8];
        Vn[i] = *(const short8*)&Vt[i * 512 + l8];
      }
      bMn[0] = *(const int4*)&mask[boff + ktn * 32];
      bMn[1] = *(const int4*)&mask[boff + ktn * 32 + 16];
      bSn[0] = *(const float4*)&spat[boff + ktn * 32];
      bSn[1] = *(const float4*)&spat[boff + ktn * 32 + 16];
    }

    // ---- swapped QK^T: dots[j] lane(hb,ln) = S[k=j*16+hb*4+r][q=ln] ----
    f32x4 dots[2] = {};
    __builtin_amdgcn_s_setprio(1);
#pragma unroll
    for (int kc = 0; kc < 2; ++kc)
#pragma unroll
      for (int j = 0; j < 2; ++j) {
        dots[j] = MFMA16(Kc[kc * 2 + j], qfh[kc], dots[j]);
        dots[j] = MFMA16(Kc[kc * 2 + j], qfl[kc], dots[j]);
      }
    __builtin_amdgcn_s_setprio(0);

    // ---- bias (mask? spat*log2e : -inf) added per-lane ----
    float lg[2][4];
    lg[0][0] = bMc[0].x ? fmaf(bSc[0].x, LOG2E, dots[0][0]) : NEGINF;
    lg[0][1] = bMc[0].y ? fmaf(bSc[0].y, LOG2E, dots[0][1]) : NEGINF;
    lg[0][2] = bMc[0].z ? fmaf(bSc[0].z, LOG2E, dots[0][2]) : NEGINF;
    lg[0][3] = bMc[0].w ? fmaf(bSc[0].w, LOG2E, dots[0][3]) : NEGINF;
    lg[1][0] = bMc[1].x ? fmaf(bSc[1].x, LOG2E, dots[1][0]) : NEGINF;
    lg[1][1] = bMc[1].y ? fmaf(bSc[1].y, LOG2E, dots[1][1]) : NEGINF;
    lg[1][2] = bMc[1].z ? fmaf(bSc[1].z, LOG2E, dots[1][2]) : NEGINF;
    lg[1][3] = bMc[1].w ? fmaf(bSc[1].w, LOG2E, dots[1][3]) : NEGINF;

    // ---- per-lane online softmax (q=ln), defer-max THR=8 ----
    float pmax = fmaxf(fmaxf(fmaxf(lg[0][0], lg[0][1]), fmaxf(lg[0][2], lg[0][3])),
                       fmaxf(fmaxf(lg[1][0], lg[1][1]), fmaxf(lg[1][2], lg[1][3])));
    pmax = fmaxf(pmax, __shfl_xor(pmax, 16));
    pmax = fmaxf(pmax, __shfl_xor(pmax, 32));
    if (__any(pmax > m_run + DEFER_THR)) {
      const float mn = fmaxf(m_run, pmax);
      const float fac = exp2f(m_run - mn);
      m_run = mn;
#pragma unroll
      for (int r = 0; r < 4; ++r) {
        const float fr = bpermf(hb * 4 + r, fac);
        O[0][r] *= fr; O[1][r] *= fr; O[2][r] *= fr; O[3][r] *= fr;
        l_acc[r] *= fr;
      }
    }
    float p[2][4];
#pragma unroll
    for (int j = 0; j < 2; ++j)
#pragma unroll
      for (int r = 0; r < 4; ++r)
        p[j][r] = exp2f(lg[j][r] - m_run);

    // ---- pack bf16 + exchange to A-fragment via per-wave LDS ----
    {
      uint2 w0, w1;
      w0.x = cvtpk(p[0][0], p[0][1]); w0.y = cvtpk(p[0][2], p[0][3]);
      w1.x = cvtpk(p[1][0], p[1][1]); w1.y = cvtpk(p[1][2], p[1][3]);
      *(uint2*)&Pw[ln * 20 + hb * 2]     = w0;
      *(uint2*)&Pw[ln * 20 + 8 + hb * 2] = w1;
    }
    const short8 pf = *(const short8*)&Pw[ln * 20 + hb * 4];

    // ---- PV + row-sum via ones-MFMA ----
    __builtin_amdgcn_s_setprio(1);
#pragma unroll
    for (int j2 = 0; j2 < 4; ++j2)
      O[j2] = MFMA16(pf, Vc[j2], O[j2]);
    l_acc = MFMA16(pf, ones, l_acc);
    __builtin_amdgcn_s_setprio(0);
  };

  for (int kt = kt0; kt < kt0 + 32; kt += 2) {
    body(Ka, Va, Kb, Vb, bMa, bSa, bMb, bSb, kt + 1);
    body(Kb, Vb, Ka, Va, bMb, bSb, bMa, bSa, (kt + 2) & 63);
  }

  // ---- epilogue: write unnormalized partial O + per-row m,l ----
  const int g = ((b * H_ + w) * 128 + qt) * 2 + half;
  float* Opg = Op + (size_t)g * 1024;
#pragma unroll
  for (int j2 = 0; j2 < 4; ++j2)
#pragma unroll
    for (int r = 0; r < 4; ++r)
      Opg[(hb * 4 + r) * 64 + j2 * 16 + ln] = O[j2][r];
  if (lane < 16) MP[g * 16 + lane] = m_run;       // hb=0, q=ln
  if (ln == 0) {
#pragma unroll
    for (int r = 0; r < 4; ++r) LP[g * 16 + hb * 4 + r] = l_acc[r];
  }
}

// ---------------------------------------------------------------------------
// Kernel 3b: combine the two kv-halves, normalize, write split-bf16 attn-out.
// grid 1024 x 256; thread -> (row, 8 cols).
// ---------------------------------------------------------------------------
__global__ __launch_bounds__(256) void k_comb(
    const float* __restrict__ Op, const float* __restrict__ MP,
    const float* __restrict__ LP,
    u16* __restrict__ ah, u16* __restrict__ al)
{
  const int i = blockIdx.x * 256 + threadIdx.x;   // [0, 262144)
  const int row = i >> 5, cg = i & 31;
  const int c0 = cg * 8, h = c0 >> 6, d0 = c0 & 63;
  const int b = row >> 11, nn = row & 2047, qt = nn >> 4, q = nn & 15;
  const int g0 = ((b * H_ + h) * 128 + qt) * 2;

  const float m1 = MP[g0 * 16 + q],       m2 = MP[(g0 + 1) * 16 + q];
  const float l1 = LP[g0 * 16 + q],       l2 = LP[(g0 + 1) * 16 + q];
  const float mm = fmaxf(m1, m2);
  const float f1 = exp2f(m1 - mm), f2 = exp2f(m2 - mm);
  const float inv = 1.0f / (l1 * f1 + l2 * f2);

  const float* p1 = Op + (size_t)g0 * 1024 + q * 64 + d0;
  const float* p2 = p1 + 1024;
  const f32x4 a1 = *(const f32x4*)p1, b1 = *(const f32x4*)(p1 + 4);
  const f32x4 a2 = *(const f32x4*)p2, b2 = *(const f32x4*)(p2 + 4);

  u16v8 hh, ll;
#pragma unroll
  for (int e = 0; e < 4; ++e) {
    const float v = (a1[e] * f1 + a2[e] * f2) * inv;
    split2(v, &hh.v[e], &ll.v[e]);
  }
#pragma unroll
  for (int e = 0; e < 4; ++e) {
    const float v = (b1[e] * f1 + b2[e] * f2) * inv;
    split2(v, &hh.v[e + 4], &ll.v[e + 4]);
  }
  *(u16v8*)&ah[row * DIMX + c0] = hh;
  *(u16v8*)&al[row * DIMX + c0] = ll;
}

// ---------------------------------------------------------------------------
// Kernel 4: out = aout @ Wout + b_out. M=8192, N=256, K=256.
// ---------------------------------------------------------------------------
__global__ __launch_bounds__(256) void k_out(
    const u16* __restrict__ ahg, const u16* __restrict__ alg,
    const u16* __restrict__ wh, const u16* __restrict__ wl,
    const float* __restrict__ bout, float* __restrict__ out)
{
  const int w = threadIdx.x >> 6, lane = threadIdx.x & 63;
  const int ln = lane & 15, hb = lane >> 4;
  const int arow = blockIdx.y * 64 + w * 16 + ln;
  const int colb = blockIdx.x * 64;

  f32x4 acc[4] = {};
  for (int ks = 0; ks < 8; ++ks) {
    const int k0 = ks * 32 + hb * 8;
    short8 a_h = *(const short8*)&ahg[arow * 256 + k0];
    short8 a_l = *(const short8*)&alg[arow * 256 + k0];
#pragma unroll
    for (int j = 0; j < 4; ++j) {
      const int c = colb + j * 16 + ln;
      short8 b_h = *(const short8*)&wh[c * 256 + k0];
      short8 b_l = *(const short8*)&wl[c * 256 + k0];
      acc[j] = MFMA16(a_h, b_h, acc[j]);
      acc[j] = MFMA16(a_l, b_h, acc[j]);
      acc[j] = MFMA16(a_h, b_l, acc[j]);
    }
  }
  const int mbase = blockIdx.y * 64 + w * 16 + hb * 4;
#pragma unroll
  for (int j = 0; j < 4; ++j) {
    const int c = colb + j * 16 + ln;
    const float bb = bout[c];
#pragma unroll
    for (int r = 0; r < 4; ++r)
      out[(mbase + r) * 256 + c] = acc[j][r] + bb;
  }
}

// ---------------------------------------------------------------------------
extern "C" void kernel_launch(void* const* d_in, const int* in_sizes, int n_in,
                              void* d_out, int out_size, void* d_ws, size_t ws_size,
                              hipStream_t stream)
{
  (void)in_sizes; (void)n_in; (void)out_size; (void)ws_size;
  const float* x    = (const float*)d_in[0];
  const int*   mask = (const int*)d_in[1];
  const float* spat = (const float*)d_in[2];
  const float* wq   = (const float*)d_in[3];
  const float* wo   = (const float*)d_in[4];
  const float* bout = (const float*)d_in[5];
  float* out = (float*)d_out;

  char* ws = (char*)d_ws;
  size_t o = 0;
  auto alloc = [&](size_t bytes) -> char* {
    char* p = ws + o;
    o += (bytes + 255) & ~(size_t)255;
    return p;
  };
  u16* xh  = (u16*)alloc((size_t)M_ * 256 * 2);
  u16* xl  = (u16*)alloc((size_t)M_ * 256 * 2);
  u16* wqh = (u16*)alloc((size_t)768 * 256 * 2);
  u16* wql = (u16*)alloc((size_t)768 * 256 * 2);
  u16* woh = (u16*)alloc((size_t)256 * 256 * 2);
  u16* wol = (u16*)alloc((size_t)256 * 256 * 2);
  u16* qh  = (u16*)alloc((size_t)16 * N_ * DH_ * 2);
  u16* ql  = (u16*)alloc((size_t)16 * N_ * DH_ * 2);
  u16* kf  = (u16*)alloc((size_t)16 * N_ * DH_ * 2);
  u16* vf  = (u16*)alloc((size_t)16 * N_ * DH_ * 2);
  u16* ah  = (u16*)alloc((size_t)M_ * 256 * 2);
  u16* al  = (u16*)alloc((size_t)M_ * 256 * 2);
  float* Op = (float*)alloc((size_t)4096 * 1024 * 4);  // 16.8 MB partials
  float* MP = (float*)alloc((size_t)4096 * 16 * 4);
  float* LP = (float*)alloc((size_t)4096 * 16 * 4);

  hipLaunchKernelGGL(k_split, dim3(3072), dim3(256), 0, stream,
                     x, wq, wo, xh, xl, wqh, wql, woh, wol);
  hipLaunchKernelGGL(k_qkv, dim3(12, 128), dim3(256), 0, stream,
                     xh, xl, wqh, wql, qh, ql, kf, vf);
  hipLaunchKernelGGL(k_attn, dim3(1024), dim3(256), 0, stream,
                     qh, ql, kf, vf, mask, spat, Op, MP, LP);
  hipLaunchKernelGGL(k_comb, dim3(1024), dim3(256), 0, stream,
                     Op, MP, LP, ah, al);
  hipLaunchKernelGGL(k_out, dim3(4, 128), dim3(256), 0, stream,
                     ah, al, woh, wol, bout, out);
}

// Round 6
// 171.443 us; speedup vs baseline: 1.0975x; 1.0975x over previous
//
#include <hip/hip_runtime.h>

// ============================================================================
// AttentionWithSpatial: x@Wqkv -> masked/biased 4-head attention -> @Wout+b
// b=4, n=2048, dim=256, heads=4, dhead=64, scale=0.125
//
// R5 post-mortem: k_attn is L2-BW bound (~12KB/wave-iter, 200MB/XCD). R6:
//  - k_bias: prefuse mask+spat -> fp16 FRAGMENT-MAJOR bias (log2e folded).
//    Bias in k_attn: 1 coalesced 16B/lane load per iter (was 4KB scattered).
//  - k_attn blocks = (b, h, qt-quad): 4 waves share one head's K/V, staged
//    in LDS once per block-iter (8KB vs 32KB). T14 split staging, 1 barrier.
//  - (b,h)->XCD pinned (bid&7): 2MB K/V slice L2-resident per XCD.
//  - no KV-split / k_comb; epilogue writes split-bf16 directly.
// ============================================================================

#define B_   4
#define N_   2048
#define H_   4
#define DH_  64
#define DIMX 256
#define M_   (B_*N_)   // 8192

#define LOG2E  1.4426950408889634f
#define NEGINF (-1e30f)
#define DEFER_THR 8.0f

typedef __attribute__((ext_vector_type(8))) short short8;
typedef __attribute__((ext_vector_type(4))) float f32x4;
typedef unsigned short u16;
typedef unsigned int   u32;

#define MFMA16(a,b,c) __builtin_amdgcn_mfma_f32_16x16x32_bf16((a),(b),(c),0,0,0)

__device__ __forceinline__ u16 f2bf(float f) {
  u32 u = __builtin_bit_cast(u32, f);
  u += 0x7fffu + ((u >> 16) & 1u);   // RNE
  return (u16)(u >> 16);
}
__device__ __forceinline__ float bf2f(u16 h) {
  u32 u = ((u32)h) << 16;
  return __builtin_bit_cast(float, u);
}
__device__ __forceinline__ void split2(float f, u16* hi, u16* lo) {
  u16 h = f2bf(f);
  *hi = h;
  *lo = f2bf(f - bf2f(h));
}
__device__ __forceinline__ float bpermf(int srclane, float v) {
  return __builtin_bit_cast(float,
      __builtin_amdgcn_ds_bpermute(srclane << 2, __builtin_bit_cast(int, v)));
}
__device__ __forceinline__ u32 cvtpk(float lo, float hi) {
  u32 r;
  asm("v_cvt_pk_bf16_f32 %0, %1, %2" : "=v"(r) : "v"(lo), "v"(hi));
  return r;
}

struct u16v4 { u16 a, b, c, d; };
struct u16v8 { u16 v[8]; };

// ---------------------------------------------------------------------------
// Kernel 1: split x into hi/lo bf16 (float4 path); transpose+split Wqkv/Wout.
// ---------------------------------------------------------------------------
__global__ __launch_bounds__(256) void k_split(
    const float* __restrict__ x, const float* __restrict__ wq,
    const float* __restrict__ wo,
    u16* __restrict__ xh, u16* __restrict__ xl,
    u16* __restrict__ wqh, u16* __restrict__ wql,
    u16* __restrict__ woh, u16* __restrict__ wol)
{
  const int NX4 = (M_ * DIMX) / 4;  // 524288
  const int NWQ = 768 * 256;        // 196608
  const int NWO = 256 * 256;        // 65536
  int i = blockIdx.x * 256 + threadIdx.x;
  if (i < NX4) {
    const float4 v = ((const float4*)x)[i];
    u16v4 hv, lv;
    split2(v.x, &hv.a, &lv.a);
    split2(v.y, &hv.b, &lv.b);
    split2(v.z, &hv.c, &lv.c);
    split2(v.w, &hv.d, &lv.d);
    ((u16v4*)xh)[i] = hv;
    ((u16v4*)xl)[i] = lv;
  } else if (i < NX4 + NWQ) {
    int j = i - NX4;
    int c = j >> 8, k = j & 255;            // out layout [c][k]
    split2(wq[k * 768 + c], &wqh[j], &wql[j]);
  } else if (i < NX4 + NWQ + NWO) {
    int j = i - NX4 - NWQ;
    int c = j >> 8, k = j & 255;
    split2(wo[k * 256 + c], &woh[j], &wol[j]);
  }
}

// ---------------------------------------------------------------------------
// Kernel 1b: prefuse bias = mask? spat*log2e : -1e4, fp16, FRAGMENT-MAJOR:
// record r = (((b*128+qt)*64 + kt)*64 + lane); elems e=j*4+rr ->
//   (q = qt*16 + (lane&15), k = kt*32 + j*16 + (lane>>4)*4 + rr)
// Writes coalesced 16B/thread; reads 16x16 int tiles (64B-granule efficient).
// ---------------------------------------------------------------------------
__global__ __launch_bounds__(256) void k_bias(
    const int* __restrict__ mask, const float* __restrict__ spat,
    u16* __restrict__ biasF)
{
  const int r = blockIdx.x * 256 + threadIdx.x;      // [0, 2097152)
  const int lane = r & 63;
  const int kt = (r >> 6) & 63;
  const int qt = (r >> 12) & 127;
  const int b  = r >> 19;
  const int ln = lane & 15, hb = lane >> 4;
  const int q  = qt * 16 + ln;
  const int c0 = kt * 32 + hb * 4;
  const int base = (b * N_ + q) * N_ + c0;

  const int4   m0 = *(const int4*)&mask[base];
  const int4   m1 = *(const int4*)&mask[base + 16];
  const float4 s0 = *(const float4*)&spat[base];
  const float4 s1 = *(const float4*)&spat[base + 16];

  const float NB = -10000.0f;
  u16v8 o;
  o.v[0] = __builtin_bit_cast(u16, (_Float16)(m0.x ? s0.x * LOG2E : NB));
  o.v[1] = __builtin_bit_cast(u16, (_Float16)(m0.y ? s0.y * LOG2E : NB));
  o.v[2] = __builtin_bit_cast(u16, (_Float16)(m0.z ? s0.z * LOG2E : NB));
  o.v[3] = __builtin_bit_cast(u16, (_Float16)(m0.w ? s0.w * LOG2E : NB));
  o.v[4] = __builtin_bit_cast(u16, (_Float16)(m1.x ? s1.x * LOG2E : NB));
  o.v[5] = __builtin_bit_cast(u16, (_Float16)(m1.y ? s1.y * LOG2E : NB));
  o.v[6] = __builtin_bit_cast(u16, (_Float16)(m1.z ? s1.z * LOG2E : NB));
  o.v[7] = __builtin_bit_cast(u16, (_Float16)(m1.w ? s1.w * LOG2E : NB));
  *(u16v8*)&biasF[(size_t)r * 8] = o;
}

// ---------------------------------------------------------------------------
// Kernel 2: QKV GEMM. M=8192, N=768, K=256. Block = 4 waves, 64x64 tile.
// Q pre-scaled by 0.125*log2e, split hi/lo, layout [bh][n][d].
// K fragment-major: (bh*64+kt)*2048 + (kc*2+j)*512 + lane*8 + e
// V fragment-major: (bh*64+kt)*2048 + j2*512 + lane*8 + e  (V^T fragments)
// ---------------------------------------------------------------------------
__global__ __launch_bounds__(256) void k_qkv(
    const u16* __restrict__ xh, const u16* __restrict__ xl,
    const u16* __restrict__ wh, const u16* __restrict__ wl,
    u16* __restrict__ qh, u16* __restrict__ ql,
    u16* __restrict__ kf, u16* __restrict__ vf)
{
  const int w = threadIdx.x >> 6, lane = threadIdx.x & 63;
  const int ln = lane & 15, hb = lane >> 4;
  const int arow = blockIdx.y * 64 + w * 16 + ln;
  const int colb = blockIdx.x * 64;

  f32x4 acc[4] = {};
  for (int ks = 0; ks < 8; ++ks) {
    const int k0 = ks * 32 + hb * 8;
    short8 a_h = *(const short8*)&xh[arow * 256 + k0];
    short8 a_l = *(const short8*)&xl[arow * 256 + k0];
#pragma unroll
    for (int j = 0; j < 4; ++j) {
      const int c = colb + j * 16 + ln;
      short8 b_h = *(const short8*)&wh[c * 256 + k0];
      short8 b_l = *(const short8*)&wl[c * 256 + k0];
      acc[j] = MFMA16(a_h, b_h, acc[j]);
      acc[j] = MFMA16(a_l, b_h, acc[j]);
      acc[j] = MFMA16(a_h, b_l, acc[j]);
    }
  }
  const int mbase = blockIdx.y * 64 + w * 16 + hb * 4;
#pragma unroll
  for (int j = 0; j < 4; ++j) {
    const int c = colb + j * 16 + ln;
    const int which = c >> 8;        // 0=q 1=k 2=v
    const int hd = c & 255;
    const int hh = hd >> 6, d = hd & 63;
#pragma unroll
    for (int r = 0; r < 4; ++r) {
      const int m = mbase + r;
      const int bb = m >> 11, nn = m & 2047;
      const int bh = bb * H_ + hh;
      float v = acc[j][r];
      if (which == 0) {
        const int off = (bh * N_ + nn) * DH_ + d;
        v *= (0.125f * LOG2E);                 // scale + exp2-domain fold
        split2(v, &qh[off], &ql[off]);
      } else if (which == 1) {
        const int ktile = nn >> 5, jj = (nn >> 4) & 1, lnn = nn & 15;
        const int kc = d >> 5, hbb = (d >> 3) & 3, e = d & 7;
        const int off = (bh * 64 + ktile) * 2048 + (kc * 2 + jj) * 512
                      + (hbb * 16 + lnn) * 8 + e;
        kf[off] = f2bf(v);
      } else {
        const int ktile = nn >> 5, hbb = (nn >> 3) & 3, e = nn & 7;
        const int j2 = d >> 4, lnn = d & 15;
        const int off = (bh * 64 + ktile) * 2048 + j2 * 512
                      + (hbb * 16 + lnn) * 8 + e;
        vf[off] = f2bf(v);
      }
    }
  }
}

// ---------------------------------------------------------------------------
// Kernel 3: flash attention. grid 512: bid = qq*16 + bh, bh=(b*4+h) -> XCD
// bh&7 pinned (K/V slice L2-resident). 4 waves = 4 q-tiles of the SAME head:
// K/V staged in LDS once per block-iter (reg-staged, issue-early/write-late),
// double-buffered, ONE barrier/iter. Bias: 1 coalesced fp16 load/lane/iter.
// Swapped QK^T, per-lane softmax, defer-max, P-exchange via per-wave LDS.
// ---------------------------------------------------------------------------
__global__ __launch_bounds__(256) void k_attn(
    const u16* __restrict__ qhg, const u16* __restrict__ qlg,
    const u16* __restrict__ kfg, const u16* __restrict__ vfg,
    const u16* __restrict__ biasF,
    u16* __restrict__ ah, u16* __restrict__ al)
{
  __shared__ __align__(16) u16 KL[2][2048];    // 8 KB  (32x64 bf16 tile)
  __shared__ __align__(16) u16 VL[2][2048];    // 8 KB  (V^T fragments)
  __shared__ __align__(16) u32 Pbuf[4][320];   // 5 KB, per-wave P exchange

  const int bid = blockIdx.x;
  const int bh = bid & 15, qq = bid >> 4;
  const int b = bh >> 2, h = bh & 3;
  const int tid = threadIdx.x;
  const int w = tid >> 6, lane = tid & 63;
  const int qt = qq * 4 + w;                   // this wave's q-tile [0,128)
  const int ln = lane & 15, hb = lane >> 4;

  // ---- Q fragments (pre-scaled by 0.125*log2e), hi/lo ----
  short8 qfh[2], qfl[2];
  {
    const int base = ((b * H_ + h) * N_ + qt * 16 + ln) * DH_;
    qfh[0] = *(const short8*)&qhg[base + hb * 8];
    qfh[1] = *(const short8*)&qhg[base + 32 + hb * 8];
    qfl[0] = *(const short8*)&qlg[base + hb * 8];
    qfl[1] = *(const short8*)&qlg[base + 32 + hb * 8];
  }

  const u16* Kt0 = kfg + (size_t)((b * H_ + h) * 64) * 2048;
  const u16* Vt0 = vfg + (size_t)((b * H_ + h) * 64) * 2048;
  const u16* Bt0 = biasF + (size_t)((b * 128 + qt) * 64) * 512;
  const int stoff = w * 512 + lane * 8;  // this thread's staging slot (16B)
  const int l8 = lane * 8;

  short8 ones;
#pragma unroll
  for (int i = 0; i < 8; ++i) ones[i] = (short)0x3F80;   // bf16 1.0

  f32x4 O[4] = {};
  f32x4 l_acc = {};
  float m_run = NEGINF;
  u32* Pw = &Pbuf[w][0];

  short8 kst, vst, bc, bn;

  // ---- prologue: stage tile 0, load bias 0 ----
  kst = *(const short8*)&Kt0[stoff];
  vst = *(const short8*)&Vt0[stoff];
  bc  = *(const short8*)&Bt0[l8];
  *(short8*)&KL[0][stoff] = kst;
  *(short8*)&VL[0][stoff] = vst;
  __syncthreads();

  int cur = 0;
  for (int kt = 0; kt < 64; ++kt) {
    const int ktn = (kt + 1) & 63;

    // ---- issue next-tile loads early (hide HBM/L2 latency under compute) --
    kst = *(const short8*)&Kt0[ktn * 2048 + stoff];
    vst = *(const short8*)&Vt0[ktn * 2048 + stoff];
    bn  = *(const short8*)&Bt0[ktn * 512 + l8];

    // ---- swapped QK^T from LDS: dots[j] lane(hb,ln)=S[k=j*16+hb*4+r][q=ln]
    f32x4 dots[2] = {};
    __builtin_amdgcn_s_setprio(1);
#pragma unroll
    for (int kc = 0; kc < 2; ++kc)
#pragma unroll
      for (int j = 0; j < 2; ++j) {
        const short8 kfr = *(const short8*)&KL[cur][(kc * 2 + j) * 512 + l8];
        dots[j] = MFMA16(kfr, qfh[kc], dots[j]);
        dots[j] = MFMA16(kfr, qfl[kc], dots[j]);
      }
    __builtin_amdgcn_s_setprio(0);

    // ---- bias add (fp16 regs from last iter) ----
    float lg[2][4];
#pragma unroll
    for (int j = 0; j < 2; ++j)
#pragma unroll
      for (int r = 0; r < 4; ++r) {
        const float bv = (float)__builtin_bit_cast(_Float16, (u16)bc[j * 4 + r]);
        lg[j][r] = dots[j][r] + bv;
      }

    // ---- per-lane online softmax (q=ln), defer-max THR=8 ----
    float pmax = fmaxf(fmaxf(fmaxf(lg[0][0], lg[0][1]), fmaxf(lg[0][2], lg[0][3])),
                       fmaxf(fmaxf(lg[1][0], lg[1][1]), fmaxf(lg[1][2], lg[1][3])));
    pmax = fmaxf(pmax, __shfl_xor(pmax, 16));
    pmax = fmaxf(pmax, __shfl_xor(pmax, 32));
    if (__any(pmax > m_run + DEFER_THR)) {
      const float mn = fmaxf(m_run, pmax);
      const float fac = exp2f(m_run - mn);
      m_run = mn;
#pragma unroll
      for (int r = 0; r < 4; ++r) {
        const float fr = bpermf(hb * 4 + r, fac);
        O[0][r] *= fr; O[1][r] *= fr; O[2][r] *= fr; O[3][r] *= fr;
        l_acc[r] *= fr;
      }
    }
    float p[2][4];
#pragma unroll
    for (int j = 0; j < 2; ++j)
#pragma unroll
      for (int r = 0; r < 4; ++r)
        p[j][r] = exp2f(lg[j][r] - m_run);

    // ---- pack bf16 + exchange to A-fragment via per-wave LDS ----
    {
      uint2 w0, w1;
      w0.x = cvtpk(p[0][0], p[0][1]); w0.y = cvtpk(p[0][2], p[0][3]);
      w1.x = cvtpk(p[1][0], p[1][1]); w1.y = cvtpk(p[1][2], p[1][3]);
      *(uint2*)&Pw[ln * 20 + hb * 2]     = w0;
      *(uint2*)&Pw[ln * 20 + 8 + hb * 2] = w1;
    }
    const short8 pf = *(const short8*)&Pw[ln * 20 + hb * 4];

    // ---- PV + row-sum via ones-MFMA (V frags from LDS) ----
    __builtin_amdgcn_s_setprio(1);
#pragma unroll
    for (int j2 = 0; j2 < 4; ++j2) {
      const short8 vfr = *(const short8*)&VL[cur][j2 * 512 + l8];
      O[j2] = MFMA16(pf, vfr, O[j2]);
    }
    l_acc = MFMA16(pf, ones, l_acc);
    __builtin_amdgcn_s_setprio(0);

    // ---- write staged tile into the other buffer (late write, T14) ----
    *(short8*)&KL[cur ^ 1][stoff] = kst;
    *(short8*)&VL[cur ^ 1][stoff] = vst;
    __syncthreads();
    bc = bn;
    cur ^= 1;
  }

  // ---- epilogue: normalize, write attn-out split bf16, layout [m][h*64+d]
  float inv[4];
#pragma unroll
  for (int r = 0; r < 4; ++r) inv[r] = 1.0f / l_acc[r];
  const int mrow = b * N_ + qt * 16 + hb * 4;
#pragma unroll
  for (int j2 = 0; j2 < 4; ++j2) {
    const int col = h * 64 + j2 * 16 + ln;
#pragma unroll
    for (int r = 0; r < 4; ++r) {
      const float v = O[j2][r] * inv[r];
      split2(v, &ah[(mrow + r) * DIMX + col], &al[(mrow + r) * DIMX + col]);
    }
  }
}

// ---------------------------------------------------------------------------
// Kernel 4: out = aout @ Wout + b_out. M=8192, N=256, K=256.
// ---------------------------------------------------------------------------
__global__ __launch_bounds__(256) void k_out(
    const u16* __restrict__ ahg, const u16* __restrict__ alg,
    const u16* __restrict__ wh, const u16* __restrict__ wl,
    const float* __restrict__ bout, float* __restrict__ out)
{
  const int w = threadIdx.x >> 6, lane = threadIdx.x & 63;
  const int ln = lane & 15, hb = lane >> 4;
  const int arow = blockIdx.y * 64 + w * 16 + ln;
  const int colb = blockIdx.x * 64;

  f32x4 acc[4] = {};
  for (int ks = 0; ks < 8; ++ks) {
    const int k0 = ks * 32 + hb * 8;
    short8 a_h = *(const short8*)&ahg[arow * 256 + k0];
    short8 a_l = *(const short8*)&alg[arow * 256 + k0];
#pragma unroll
    for (int j = 0; j < 4; ++j) {
      const int c = colb + j * 16 + ln;
      short8 b_h = *(const short8*)&wh[c * 256 + k0];
      short8 b_l = *(const short8*)&wl[c * 256 + k0];
      acc[j] = MFMA16(a_h, b_h, acc[j]);
      acc[j] = MFMA16(a_l, b_h, acc[j]);
      acc[j] = MFMA16(a_h, b_l, acc[j]);
    }
  }
  const int mbase = blockIdx.y * 64 + w * 16 + hb * 4;
#pragma unroll
  for (int j = 0; j < 4; ++j) {
    const int c = colb + j * 16 + ln;
    const float bb = bout[c];
#pragma unroll
    for (int r = 0; r < 4; ++r)
      out[(mbase + r) * 256 + c] = acc[j][r] + bb;
  }
}

// ---------------------------------------------------------------------------
extern "C" void kernel_launch(void* const* d_in, const int* in_sizes, int n_in,
                              void* d_out, int out_size, void* d_ws, size_t ws_size,
                              hipStream_t stream)
{
  (void)in_sizes; (void)n_in; (void)out_size; (void)ws_size;
  const float* x    = (const float*)d_in[0];
  const int*   mask = (const int*)d_in[1];
  const float* spat = (const float*)d_in[2];
  const float* wq   = (const float*)d_in[3];
  const float* wo   = (const float*)d_in[4];
  const float* bout = (const float*)d_in[5];
  float* out = (float*)d_out;

  char* ws = (char*)d_ws;
  size_t o = 0;
  auto alloc = [&](size_t bytes) -> char* {
    char* p = ws + o;
    o += (bytes + 255) & ~(size_t)255;
    return p;
  };
  u16* xh  = (u16*)alloc((size_t)M_ * 256 * 2);
  u16* xl  = (u16*)alloc((size_t)M_ * 256 * 2);
  u16* wqh = (u16*)alloc((size_t)768 * 256 * 2);
  u16* wql = (u16*)alloc((size_t)768 * 256 * 2);
  u16* woh = (u16*)alloc((size_t)256 * 256 * 2);
  u16* wol = (u16*)alloc((size_t)256 * 256 * 2);
  u16* qh  = (u16*)alloc((size_t)16 * N_ * DH_ * 2);
  u16* ql  = (u16*)alloc((size_t)16 * N_ * DH_ * 2);
  u16* kf  = (u16*)alloc((size_t)16 * N_ * DH_ * 2);
  u16* vf  = (u16*)alloc((size_t)16 * N_ * DH_ * 2);
  u16* ah  = (u16*)alloc((size_t)M_ * 256 * 2);
  u16* al  = (u16*)alloc((size_t)M_ * 256 * 2);
  u16* biasF = (u16*)alloc((size_t)4 * 128 * 64 * 512 * 2);  // 33.5 MB fp16

  hipLaunchKernelGGL(k_bias, dim3(8192), dim3(256), 0, stream,
                     mask, spat, biasF);
  hipLaunchKernelGGL(k_split, dim3(3072), dim3(256), 0, stream,
                     x, wq, wo, xh, xl, wqh, wql, woh, wol);
  hipLaunchKernelGGL(k_qkv, dim3(12, 128), dim3(256), 0, stream,
                     xh, xl, wqh, wql, qh, ql, kf, vf);
  hipLaunchKernelGGL(k_attn, dim3(512), dim3(256), 0, stream,
                     qh, ql, kf, vf, biasF, ah, al);
  hipLaunchKernelGGL(k_out, dim3(4, 128), dim3(256), 0, stream,
                     ah, al, woh, wol, bout, out);
}

// Round 8
// 164.397 us; speedup vs baseline: 1.1446x; 1.0429x over previous
//
#include <hip/hip_runtime.h>

// ============================================================================
// AttentionWithSpatial: x@Wqkv -> masked/biased 4-head attention -> @Wout+b
// b=4, n=2048, dim=256, heads=4, dhead=64, scale=0.125
//
// R7 post-mortem: Op alias overran (xh+xl is 8MB, not 16MB) into qh/ql/MP/LP
// -> NaN. R8 = same plan, safe memory:
//  - Op half0 -> xh+xl region (exactly 8MB, dead after k_qkv),
//    Op half1 -> d_out used as scratch (exactly 8MB, overwritten by k_out),
//    MP/LP -> wqh/wql (dead after k_qkv). ws high-water = R6's (known good).
//  - KV-split=2: grid 1024, 4 blocks/CU, 16 waves/CU (TLP for latency hiding).
//  - k_prep = fused bias-prefuse + x/W split.
// ============================================================================

#define B_   4
#define N_   2048
#define H_   4
#define DH_  64
#define DIMX 256
#define M_   (B_*N_)   // 8192

#define LOG2E  1.4426950408889634f
#define NEGINF (-1e30f)
#define DEFER_THR 8.0f

typedef __attribute__((ext_vector_type(8))) short short8;
typedef __attribute__((ext_vector_type(4))) float f32x4;
typedef unsigned short u16;
typedef unsigned int   u32;

#define MFMA16(a,b,c) __builtin_amdgcn_mfma_f32_16x16x32_bf16((a),(b),(c),0,0,0)

__device__ __forceinline__ u16 f2bf(float f) {
  u32 u = __builtin_bit_cast(u32, f);
  u += 0x7fffu + ((u >> 16) & 1u);   // RNE
  return (u16)(u >> 16);
}
__device__ __forceinline__ float bf2f(u16 h) {
  u32 u = ((u32)h) << 16;
  return __builtin_bit_cast(float, u);
}
__device__ __forceinline__ void split2(float f, u16* hi, u16* lo) {
  u16 h = f2bf(f);
  *hi = h;
  *lo = f2bf(f - bf2f(h));
}
__device__ __forceinline__ float bpermf(int srclane, float v) {
  return __builtin_bit_cast(float,
      __builtin_amdgcn_ds_bpermute(srclane << 2, __builtin_bit_cast(int, v)));
}
__device__ __forceinline__ u32 cvtpk(float lo, float hi) {
  u32 r;
  asm("v_cvt_pk_bf16_f32 %0, %1, %2" : "=v"(r) : "v"(lo), "v"(hi));
  return r;
}

struct u16v4 { u16 a, b, c, d; };
struct u16v8 { u16 v[8]; };

// ---------------------------------------------------------------------------
// Kernel 1 (fused prep):
//  blocks [0,8192): bias prefuse  mask? spat*log2e : -1e4  -> fp16 frag-major
//  blocks [8192,11264): x -> xh/xl split; Wqkv/Wout transpose+split
// ---------------------------------------------------------------------------
__global__ __launch_bounds__(256) void k_prep(
    const int* __restrict__ mask, const float* __restrict__ spat,
    const float* __restrict__ x, const float* __restrict__ wq,
    const float* __restrict__ wo,
    u16* __restrict__ biasF,
    u16* __restrict__ xh, u16* __restrict__ xl,
    u16* __restrict__ wqh, u16* __restrict__ wql,
    u16* __restrict__ woh, u16* __restrict__ wol)
{
  if (blockIdx.x < 8192) {
    const int r = blockIdx.x * 256 + threadIdx.x;     // [0, 2097152)
    const int lane = r & 63;
    const int kt = (r >> 6) & 63;
    const int qt = (r >> 12) & 127;
    const int b  = r >> 19;
    const int ln = lane & 15, hb = lane >> 4;
    const int q  = qt * 16 + ln;
    const int c0 = kt * 32 + hb * 4;
    const int base = (b * N_ + q) * N_ + c0;

    const int4   m0 = *(const int4*)&mask[base];
    const int4   m1 = *(const int4*)&mask[base + 16];
    const float4 s0 = *(const float4*)&spat[base];
    const float4 s1 = *(const float4*)&spat[base + 16];

    const float NB = -10000.0f;
    u16v8 o;
    o.v[0] = __builtin_bit_cast(u16, (_Float16)(m0.x ? s0.x * LOG2E : NB));
    o.v[1] = __builtin_bit_cast(u16, (_Float16)(m0.y ? s0.y * LOG2E : NB));
    o.v[2] = __builtin_bit_cast(u16, (_Float16)(m0.z ? s0.z * LOG2E : NB));
    o.v[3] = __builtin_bit_cast(u16, (_Float16)(m0.w ? s0.w * LOG2E : NB));
    o.v[4] = __builtin_bit_cast(u16, (_Float16)(m1.x ? s1.x * LOG2E : NB));
    o.v[5] = __builtin_bit_cast(u16, (_Float16)(m1.y ? s1.y * LOG2E : NB));
    o.v[6] = __builtin_bit_cast(u16, (_Float16)(m1.z ? s1.z * LOG2E : NB));
    o.v[7] = __builtin_bit_cast(u16, (_Float16)(m1.w ? s1.w * LOG2E : NB));
    *(u16v8*)&biasF[(size_t)r * 8] = o;
    return;
  }

  const int NX4 = (M_ * DIMX) / 4;  // 524288
  const int NWQ = 768 * 256;        // 196608
  const int NWO = 256 * 256;        // 65536
  int i = (blockIdx.x - 8192) * 256 + threadIdx.x;
  if (i < NX4) {
    const float4 v = ((const float4*)x)[i];
    u16v4 hv, lv;
    split2(v.x, &hv.a, &lv.a);
    split2(v.y, &hv.b, &lv.b);
    split2(v.z, &hv.c, &lv.c);
    split2(v.w, &hv.d, &lv.d);
    ((u16v4*)xh)[i] = hv;
    ((u16v4*)xl)[i] = lv;
  } else if (i < NX4 + NWQ) {
    int j = i - NX4;
    int c = j >> 8, k = j & 255;            // out layout [c][k]
    split2(wq[k * 768 + c], &wqh[j], &wql[j]);
  } else if (i < NX4 + NWQ + NWO) {
    int j = i - NX4 - NWQ;
    int c = j >> 8, k = j & 255;
    split2(wo[k * 256 + c], &woh[j], &wol[j]);
  }
}

// ---------------------------------------------------------------------------
// Kernel 2: QKV GEMM. M=8192, N=768, K=256. Block = 4 waves, 64x64 tile.
// Q pre-scaled by 0.125*log2e, split hi/lo, layout [bh][n][d].
// K fragment-major: (bh*64+kt)*2048 + (kc*2+j)*512 + lane*8 + e
// V fragment-major: (bh*64+kt)*2048 + j2*512 + lane*8 + e  (V^T fragments)
// ---------------------------------------------------------------------------
__global__ __launch_bounds__(256) void k_qkv(
    const u16* __restrict__ xh, const u16* __restrict__ xl,
    const u16* __restrict__ wh, const u16* __restrict__ wl,
    u16* __restrict__ qh, u16* __restrict__ ql,
    u16* __restrict__ kf, u16* __restrict__ vf)
{
  const int w = threadIdx.x >> 6, lane = threadIdx.x & 63;
  const int ln = lane & 15, hb = lane >> 4;
  const int arow = blockIdx.y * 64 + w * 16 + ln;
  const int colb = blockIdx.x * 64;

  f32x4 acc[4] = {};
  for (int ks = 0; ks < 8; ++ks) {
    const int k0 = ks * 32 + hb * 8;
    short8 a_h = *(const short8*)&xh[arow * 256 + k0];
    short8 a_l = *(const short8*)&xl[arow * 256 + k0];
#pragma unroll
    for (int j = 0; j < 4; ++j) {
      const int c = colb + j * 16 + ln;
      short8 b_h = *(const short8*)&wh[c * 256 + k0];
      short8 b_l = *(const short8*)&wl[c * 256 + k0];
      acc[j] = MFMA16(a_h, b_h, acc[j]);
      acc[j] = MFMA16(a_l, b_h, acc[j]);
      acc[j] = MFMA16(a_h, b_l, acc[j]);
    }
  }
  const int mbase = blockIdx.y * 64 + w * 16 + hb * 4;
#pragma unroll
  for (int j = 0; j < 4; ++j) {
    const int c = colb + j * 16 + ln;
    const int which = c >> 8;        // 0=q 1=k 2=v
    const int hd = c & 255;
    const int hh = hd >> 6, d = hd & 63;
#pragma unroll
    for (int r = 0; r < 4; ++r) {
      const int m = mbase + r;
      const int bb = m >> 11, nn = m & 2047;
      const int bh = bb * H_ + hh;
      float v = acc[j][r];
      if (which == 0) {
        const int off = (bh * N_ + nn) * DH_ + d;
        v *= (0.125f * LOG2E);                 // scale + exp2-domain fold
        split2(v, &qh[off], &ql[off]);
      } else if (which == 1) {
        const int ktile = nn >> 5, jj = (nn >> 4) & 1, lnn = nn & 15;
        const int kc = d >> 5, hbb = (d >> 3) & 3, e = d & 7;
        const int off = (bh * 64 + ktile) * 2048 + (kc * 2 + jj) * 512
                      + (hbb * 16 + lnn) * 8 + e;
        kf[off] = f2bf(v);
      } else {
        const int ktile = nn >> 5, hbb = (nn >> 3) & 3, e = nn & 7;
        const int j2 = d >> 4, lnn = d & 15;
        const int off = (bh * 64 + ktile) * 2048 + j2 * 512
                      + (hbb * 16 + lnn) * 8 + e;
        vf[off] = f2bf(v);
      }
    }
  }
}

// ---------------------------------------------------------------------------
// Kernel 3: flash attention partials, KV-split=2. grid 1024:
// bid = qq*32 + bh*2 + half; 4 waves = 4 q-tiles of SAME head share K/V in
// LDS (dbuf, 1 barrier/iter, reg-staged issue-early/write-late). Each block
// covers kt in [half*32, half*32+32). Writes unnormalized O into
// Op0 (half=0) / Op1 (half=1) + per-row m,l into MP/LP.
// ---------------------------------------------------------------------------
__global__ __launch_bounds__(256) void k_attn(
    const u16* __restrict__ qhg, const u16* __restrict__ qlg,
    const u16* __restrict__ kfg, const u16* __restrict__ vfg,
    const u16* __restrict__ biasF,
    float* __restrict__ Op0, float* __restrict__ Op1,
    float* __restrict__ MP, float* __restrict__ LP)
{
  __shared__ __align__(16) u16 KL[2][2048];    // 8 KB  (32x64 bf16 tile)
  __shared__ __align__(16) u16 VL[2][2048];    // 8 KB  (V^T fragments)
  __shared__ __align__(16) u32 Pbuf[4][320];   // 5 KB, per-wave P exchange

  const int bid = blockIdx.x;
  const int half = bid & 1;
  const int bh = (bid >> 1) & 15;
  const int qq = bid >> 5;
  const int b = bh >> 2, h = bh & 3;
  const int kt0 = half * 32;

  const int tid = threadIdx.x;
  const int w = tid >> 6, lane = tid & 63;
  const int qt = qq * 4 + w;                   // this wave's q-tile [0,128)
  const int ln = lane & 15, hb = lane >> 4;

  // ---- Q fragments (pre-scaled by 0.125*log2e), hi/lo ----
  short8 qfh[2], qfl[2];
  {
    const int base = ((b * H_ + h) * N_ + qt * 16 + ln) * DH_;
    qfh[0] = *(const short8*)&qhg[base + hb * 8];
    qfh[1] = *(const short8*)&qhg[base + 32 + hb * 8];
    qfl[0] = *(const short8*)&qlg[base + hb * 8];
    qfl[1] = *(const short8*)&qlg[base + 32 + hb * 8];
  }

  const u16* Kt0 = kfg + (size_t)((b * H_ + h) * 64) * 2048;
  const u16* Vt0 = vfg + (size_t)((b * H_ + h) * 64) * 2048;
  const u16* Bt0 = biasF + (size_t)((b * 128 + qt) * 64) * 512;
  const int stoff = w * 512 + lane * 8;  // this thread's staging slot (16B)
  const int l8 = lane * 8;

  short8 ones;
#pragma unroll
  for (int i = 0; i < 8; ++i) ones[i] = (short)0x3F80;   // bf16 1.0

  f32x4 O[4] = {};
  f32x4 l_acc = {};
  float m_run = NEGINF;
  u32* Pw = &Pbuf[w][0];

  short8 kst, vst, bc, bn;

  // ---- prologue: stage tile kt0, load bias kt0 ----
  kst = *(const short8*)&Kt0[kt0 * 2048 + stoff];
  vst = *(const short8*)&Vt0[kt0 * 2048 + stoff];
  bc  = *(const short8*)&Bt0[kt0 * 512 + l8];
  *(short8*)&KL[0][stoff] = kst;
  *(short8*)&VL[0][stoff] = vst;
  __syncthreads();

  int cur = 0;
  for (int kt = 0; kt < 32; ++kt) {
    const int ktn = kt0 + ((kt + 1) & 31);

    // ---- issue next-tile loads early (hide HBM/L2 latency under compute) --
    kst = *(const short8*)&Kt0[ktn * 2048 + stoff];
    vst = *(const short8*)&Vt0[ktn * 2048 + stoff];
    bn  = *(const short8*)&Bt0[ktn * 512 + l8];

    // ---- swapped QK^T from LDS: dots[j] lane(hb,ln)=S[k=j*16+hb*4+r][q=ln]
    f32x4 dots[2] = {};
    __builtin_amdgcn_s_setprio(1);
#pragma unroll
    for (int kc = 0; kc < 2; ++kc)
#pragma unroll
      for (int j = 0; j < 2; ++j) {
        const short8 kfr = *(const short8*)&KL[cur][(kc * 2 + j) * 512 + l8];
        dots[j] = MFMA16(kfr, qfh[kc], dots[j]);
        dots[j] = MFMA16(kfr, qfl[kc], dots[j]);
      }
    __builtin_amdgcn_s_setprio(0);

    // ---- bias add (fp16 regs from last iter) ----
    float lg[2][4];
#pragma unroll
    for (int j = 0; j < 2; ++j)
#pragma unroll
      for (int r = 0; r < 4; ++r) {
        const float bv = (float)__builtin_bit_cast(_Float16, (u16)bc[j * 4 + r]);
        lg[j][r] = dots[j][r] + bv;
      }

    // ---- per-lane online softmax (q=ln), defer-max THR=8 ----
    float pmax = fmaxf(fmaxf(fmaxf(lg[0][0], lg[0][1]), fmaxf(lg[0][2], lg[0][3])),
                       fmaxf(fmaxf(lg[1][0], lg[1][1]), fmaxf(lg[1][2], lg[1][3])));
    pmax = fmaxf(pmax, __shfl_xor(pmax, 16));
    pmax = fmaxf(pmax, __shfl_xor(pmax, 32));
    if (__any(pmax > m_run + DEFER_THR)) {
      const float mn = fmaxf(m_run, pmax);
      const float fac = exp2f(m_run - mn);
      m_run = mn;
#pragma unroll
      for (int r = 0; r < 4; ++r) {
        const float fr = bpermf(hb * 4 + r, fac);
        O[0][r] *= fr; O[1][r] *= fr; O[2][r] *= fr; O[3][r] *= fr;
        l_acc[r] *= fr;
      }
    }
    float p[2][4];
#pragma unroll
    for (int j = 0; j < 2; ++j)
#pragma unroll
      for (int r = 0; r < 4; ++r)
        p[j][r] = exp2f(lg[j][r] - m_run);

    // ---- pack bf16 + exchange to A-fragment via per-wave LDS ----
    {
      uint2 w0, w1;
      w0.x = cvtpk(p[0][0], p[0][1]); w0.y = cvtpk(p[0][2], p[0][3]);
      w1.x = cvtpk(p[1][0], p[1][1]); w1.y = cvtpk(p[1][2], p[1][3]);
      *(uint2*)&Pw[ln * 20 + hb * 2]     = w0;
      *(uint2*)&Pw[ln * 20 + 8 + hb * 2] = w1;
    }
    const short8 pf = *(const short8*)&Pw[ln * 20 + hb * 4];

    // ---- PV + row-sum via ones-MFMA (V frags from LDS) ----
    __builtin_amdgcn_s_setprio(1);
#pragma unroll
    for (int j2 = 0; j2 < 4; ++j2) {
      const short8 vfr = *(const short8*)&VL[cur][j2 * 512 + l8];
      O[j2] = MFMA16(pf, vfr, O[j2]);
    }
    l_acc = MFMA16(pf, ones, l_acc);
    __builtin_amdgcn_s_setprio(0);

    // ---- write staged tile into the other buffer (late write, T14) ----
    *(short8*)&KL[cur ^ 1][stoff] = kst;
    *(short8*)&VL[cur ^ 1][stoff] = vst;
    __syncthreads();
    bc = bn;
    cur ^= 1;
  }

  // ---- epilogue: write unnormalized partial O + per-row m,l ----
  const int gg = (b * H_ + h) * 128 + qt;          // [0, 2048)
  const int g  = gg * 2 + half;                    // MP/LP index
  float* Opg = (half ? Op1 : Op0) + (size_t)gg * 1024;
#pragma unroll
  for (int j2 = 0; j2 < 4; ++j2)
#pragma unroll
    for (int r = 0; r < 4; ++r)
      Opg[(hb * 4 + r) * 64 + j2 * 16 + ln] = O[j2][r];
  if (lane < 16) MP[g * 16 + lane] = m_run;       // hb=0, q=ln
  if (ln == 0) {
#pragma unroll
    for (int r = 0; r < 4; ++r) LP[g * 16 + hb * 4 + r] = l_acc[r];
  }
}

// ---------------------------------------------------------------------------
// Kernel 3b: combine the two kv-halves, normalize, write split-bf16 attn-out.
// grid 1024 x 256; thread -> (row, 8 cols).
// ---------------------------------------------------------------------------
__global__ __launch_bounds__(256) void k_comb(
    const float* __restrict__ Op0, const float* __restrict__ Op1,
    const float* __restrict__ MP, const float* __restrict__ LP,
    u16* __restrict__ ah, u16* __restrict__ al)
{
  const int i = blockIdx.x * 256 + threadIdx.x;   // [0, 262144)
  const int row = i >> 5, cg = i & 31;
  const int c0 = cg * 8, h = c0 >> 6, d0 = c0 & 63;
  const int b = row >> 11, nn = row & 2047, qt = nn >> 4, q = nn & 15;
  const int gg = (b * H_ + h) * 128 + qt;
  const int g0 = gg * 2;

  const float m1 = MP[g0 * 16 + q],       m2 = MP[(g0 + 1) * 16 + q];
  const float l1 = LP[g0 * 16 + q],       l2 = LP[(g0 + 1) * 16 + q];
  const float mm = fmaxf(m1, m2);
  const float f1 = exp2f(m1 - mm), f2 = exp2f(m2 - mm);
  const float inv = 1.0f / (l1 * f1 + l2 * f2);

  const float* p1 = Op0 + (size_t)gg * 1024 + q * 64 + d0;
  const float* p2 = Op1 + (size_t)gg * 1024 + q * 64 + d0;
  const f32x4 a1 = *(const f32x4*)p1, b1 = *(const f32x4*)(p1 + 4);
  const f32x4 a2 = *(const f32x4*)p2, b2 = *(const f32x4*)(p2 + 4);

  u16v8 hh, ll;
#pragma unroll
  for (int e = 0; e < 4; ++e) {
    const float v = (a1[e] * f1 + a2[e] * f2) * inv;
    split2(v, &hh.v[e], &ll.v[e]);
  }
#pragma unroll
  for (int e = 0; e < 4; ++e) {
    const float v = (b1[e] * f1 + b2[e] * f2) * inv;
    split2(v, &hh.v[e + 4], &ll.v[e + 4]);
  }
  *(u16v8*)&ah[row * DIMX + c0] = hh;
  *(u16v8*)&al[row * DIMX + c0] = ll;
}

// ---------------------------------------------------------------------------
// Kernel 4: out = aout @ Wout + b_out. M=8192, N=256, K=256.
// ---------------------------------------------------------------------------
__global__ __launch_bounds__(256) void k_out(
    const u16* __restrict__ ahg, const u16* __restrict__ alg,
    const u16* __restrict__ wh, const u16* __restrict__ wl,
    const float* __restrict__ bout, float* __restrict__ out)
{
  const int w = threadIdx.x >> 6, lane = threadIdx.x & 63;
  const int ln = lane & 15, hb = lane >> 4;
  const int arow = blockIdx.y * 64 + w * 16 + ln;
  const int colb = blockIdx.x * 64;

  f32x4 acc[4] = {};
  for (int ks = 0; ks < 8; ++ks) {
    const int k0 = ks * 32 + hb * 8;
    short8 a_h = *(const short8*)&ahg[arow * 256 + k0];
    short8 a_l = *(const short8*)&alg[arow * 256 + k0];
#pragma unroll
    for (int j = 0; j < 4; ++j) {
      const int c = colb + j * 16 + ln;
      short8 b_h = *(const short8*)&wh[c * 256 + k0];
      short8 b_l = *(const short8*)&wl[c * 256 + k0];
      acc[j] = MFMA16(a_h, b_h, acc[j]);
      acc[j] = MFMA16(a_l, b_h, acc[j]);
      acc[j] = MFMA16(a_h, b_l, acc[j]);
    }
  }
  const int mbase = blockIdx.y * 64 + w * 16 + hb * 4;
#pragma unroll
  for (int j = 0; j < 4; ++j) {
    const int c = colb + j * 16 + ln;
    const float bb = bout[c];
#pragma unroll
    for (int r = 0; r < 4; ++r)
      out[(mbase + r) * 256 + c] = acc[j][r] + bb;
  }
}

// ---------------------------------------------------------------------------
extern "C" void kernel_launch(void* const* d_in, const int* in_sizes, int n_in,
                              void* d_out, int out_size, void* d_ws, size_t ws_size,
                              hipStream_t stream)
{
  (void)in_sizes; (void)n_in; (void)out_size; (void)ws_size;
  const float* x    = (const float*)d_in[0];
  const int*   mask = (const int*)d_in[1];
  const float* spat = (const float*)d_in[2];
  const float* wq   = (const float*)d_in[3];
  const float* wo   = (const float*)d_in[4];
  const float* bout = (const float*)d_in[5];
  float* out = (float*)d_out;

  char* ws = (char*)d_ws;
  size_t o = 0;
  auto alloc = [&](size_t bytes) -> char* {
    char* p = ws + o;
    o += (bytes + 255) & ~(size_t)255;
    return p;
  };
  u16* xh  = (u16*)alloc((size_t)M_ * 256 * 2);   // 4 MB  \ Op0 alias (8 MB)
  u16* xl  = (u16*)alloc((size_t)M_ * 256 * 2);   // 4 MB  /
  u16* wqh = (u16*)alloc((size_t)768 * 256 * 2);  // 384KB -> MP alias (256KB)
  u16* wql = (u16*)alloc((size_t)768 * 256 * 2);  // 384KB -> LP alias (256KB)
  u16* woh = (u16*)alloc((size_t)256 * 256 * 2);
  u16* wol = (u16*)alloc((size_t)256 * 256 * 2);
  u16* qh  = (u16*)alloc((size_t)16 * N_ * DH_ * 2);
  u16* ql  = (u16*)alloc((size_t)16 * N_ * DH_ * 2);
  u16* kf  = (u16*)alloc((size_t)16 * N_ * DH_ * 2);
  u16* vf  = (u16*)alloc((size_t)16 * N_ * DH_ * 2);
  u16* ah  = (u16*)alloc((size_t)M_ * 256 * 2);
  u16* al  = (u16*)alloc((size_t)M_ * 256 * 2);
  u16* biasF = (u16*)alloc((size_t)4 * 128 * 64 * 512 * 2);  // 33.5 MB fp16

  // Safe scratch aliases (sizes verified):
  //  Op0 (2048*1024*4 = 8,388,608 B) <- xh+xl (4,194,304*2, contiguous,
  //      dead after k_qkv, never read later)
  //  Op1 (8,388,608 B) <- d_out (8192*256*4 = 8,388,608 B, fully
  //      overwritten by k_out at the end -> deterministic)
  //  MP/LP (4096*16*4 = 262,144 B each) <- wqh / wql (393,216 B each,
  //      dead after k_qkv, never read later)
  float* Op0 = (float*)xh;
  float* Op1 = out;
  float* MP  = (float*)wqh;
  float* LP  = (float*)wql;

  hipLaunchKernelGGL(k_prep, dim3(11264), dim3(256), 0, stream,
                     mask, spat, x, wq, wo, biasF,
                     xh, xl, wqh, wql, woh, wol);
  hipLaunchKernelGGL(k_qkv, dim3(12, 128), dim3(256), 0, stream,
                     xh, xl, wqh, wql, qh, ql, kf, vf);
  hipLaunchKernelGGL(k_attn, dim3(1024), dim3(256), 0, stream,
                     qh, ql, kf, vf, biasF, Op0, Op1, MP, LP);
  hipLaunchKernelGGL(k_comb, dim3(1024), dim3(256), 0, stream,
                     Op0, Op1, MP, LP, ah, al);
  hipLaunchKernelGGL(k_out, dim3(4, 128), dim3(256), 0, stream,
                     ah, al, woh, wol, bout, out);
}

// Round 9
// 120.995 us; speedup vs baseline: 1.5551x; 1.3587x over previous
//
#include <hip/hip_runtime.h>

// ============================================================================
// AttentionWithSpatial: x@Wqkv -> masked/biased 4-head attention -> @Wout+b
// b=4, n=2048, dim=256, heads=4, dhead=64, scale=0.125
//
// R8 post-mortem: k_qkv was the new #1 (61us, MfmaUtil 5.7%, VALU 6.6%) --
// pure latency serialization (10 dependent global loads per K-step, no
// prefetch, B loads 4x redundant per block). R9:
//  - k_qkv/k_out rewritten as LDS-staged GEMMs: B tile (64 cols x 256 K,
//    hi+lo = 64KB) staged once per block, XOR-swizzled (elem ^= (c&7)<<3);
//    2 M-subtiles per block; all 16 A-fragment loads issued upfront per
//    subtile (16 loads in flight); MFMA fed from LDS.
//  - everything else identical to passing R8 (k_prep, k_attn KV-split=2,
//    k_comb, safe ws aliasing).
// ============================================================================

#define B_   4
#define N_   2048
#define H_   4
#define DH_  64
#define DIMX 256
#define M_   (B_*N_)   // 8192

#define LOG2E  1.4426950408889634f
#define NEGINF (-1e30f)
#define DEFER_THR 8.0f

typedef __attribute__((ext_vector_type(8))) short short8;
typedef __attribute__((ext_vector_type(4))) float f32x4;
typedef unsigned short u16;
typedef unsigned int   u32;

#define MFMA16(a,b,c) __builtin_amdgcn_mfma_f32_16x16x32_bf16((a),(b),(c),0,0,0)

__device__ __forceinline__ u16 f2bf(float f) {
  u32 u = __builtin_bit_cast(u32, f);
  u += 0x7fffu + ((u >> 16) & 1u);   // RNE
  return (u16)(u >> 16);
}
__device__ __forceinline__ float bf2f(u16 h) {
  u32 u = ((u32)h) << 16;
  return __builtin_bit_cast(float, u);
}
__device__ __forceinline__ void split2(float f, u16* hi, u16* lo) {
  u16 h = f2bf(f);
  *hi = h;
  *lo = f2bf(f - bf2f(h));
}
__device__ __forceinline__ float bpermf(int srclane, float v) {
  return __builtin_bit_cast(float,
      __builtin_amdgcn_ds_bpermute(srclane << 2, __builtin_bit_cast(int, v)));
}
__device__ __forceinline__ u32 cvtpk(float lo, float hi) {
  u32 r;
  asm("v_cvt_pk_bf16_f32 %0, %1, %2" : "=v"(r) : "v"(lo), "v"(hi));
  return r;
}

struct u16v4 { u16 a, b, c, d; };
struct u16v8 { u16 v[8]; };

// ---------------------------------------------------------------------------
// Kernel 1 (fused prep):
//  blocks [0,8192): bias prefuse  mask? spat*log2e : -1e4  -> fp16 frag-major
//  blocks [8192,11264): x -> xh/xl split; Wqkv/Wout transpose+split
// ---------------------------------------------------------------------------
__global__ __launch_bounds__(256) void k_prep(
    const int* __restrict__ mask, const float* __restrict__ spat,
    const float* __restrict__ x, const float* __restrict__ wq,
    const float* __restrict__ wo,
    u16* __restrict__ biasF,
    u16* __restrict__ xh, u16* __restrict__ xl,
    u16* __restrict__ wqh, u16* __restrict__ wql,
    u16* __restrict__ woh, u16* __restrict__ wol)
{
  if (blockIdx.x < 8192) {
    const int r = blockIdx.x * 256 + threadIdx.x;     // [0, 2097152)
    const int lane = r & 63;
    const int kt = (r >> 6) & 63;
    const int qt = (r >> 12) & 127;
    const int b  = r >> 19;
    const int ln = lane & 15, hb = lane >> 4;
    const int q  = qt * 16 + ln;
    const int c0 = kt * 32 + hb * 4;
    const int base = (b * N_ + q) * N_ + c0;

    const int4   m0 = *(const int4*)&mask[base];
    const int4   m1 = *(const int4*)&mask[base + 16];
    const float4 s0 = *(const float4*)&spat[base];
    const float4 s1 = *(const float4*)&spat[base + 16];

    const float NB = -10000.0f;
    u16v8 o;
    o.v[0] = __builtin_bit_cast(u16, (_Float16)(m0.x ? s0.x * LOG2E : NB));
    o.v[1] = __builtin_bit_cast(u16, (_Float16)(m0.y ? s0.y * LOG2E : NB));
    o.v[2] = __builtin_bit_cast(u16, (_Float16)(m0.z ? s0.z * LOG2E : NB));
    o.v[3] = __builtin_bit_cast(u16, (_Float16)(m0.w ? s0.w * LOG2E : NB));
    o.v[4] = __builtin_bit_cast(u16, (_Float16)(m1.x ? s1.x * LOG2E : NB));
    o.v[5] = __builtin_bit_cast(u16, (_Float16)(m1.y ? s1.y * LOG2E : NB));
    o.v[6] = __builtin_bit_cast(u16, (_Float16)(m1.z ? s1.z * LOG2E : NB));
    o.v[7] = __builtin_bit_cast(u16, (_Float16)(m1.w ? s1.w * LOG2E : NB));
    *(u16v8*)&biasF[(size_t)r * 8] = o;
    return;
  }

  const int NX4 = (M_ * DIMX) / 4;  // 524288
  const int NWQ = 768 * 256;        // 196608
  const int NWO = 256 * 256;        // 65536
  int i = (blockIdx.x - 8192) * 256 + threadIdx.x;
  if (i < NX4) {
    const float4 v = ((const float4*)x)[i];
    u16v4 hv, lv;
    split2(v.x, &hv.a, &lv.a);
    split2(v.y, &hv.b, &lv.b);
    split2(v.z, &hv.c, &lv.c);
    split2(v.w, &hv.d, &lv.d);
    ((u16v4*)xh)[i] = hv;
    ((u16v4*)xl)[i] = lv;
  } else if (i < NX4 + NWQ) {
    int j = i - NX4;
    int c = j >> 8, k = j & 255;            // out layout [c][k]
    split2(wq[k * 768 + c], &wqh[j], &wql[j]);
  } else if (i < NX4 + NWQ + NWO) {
    int j = i - NX4 - NWQ;
    int c = j >> 8, k = j & 255;
    split2(wo[k * 256 + c], &woh[j], &wol[j]);
  }
}

// ---------------------------------------------------------------------------
// Kernel 2: QKV GEMM, LDS-staged. M=8192, N=768, K=256. grid (12, 64).
// Block: 4 waves, colb = bx*64, covers M-subtiles by*2 + {0,1}.
// B tile (hi+lo) staged once in 64KB LDS, XOR-swizzled; per subtile each
// wave issues all 16 A loads upfront, MFMA chain fed from LDS.
// Outputs (unchanged layouts):
//  Q pre-scaled by 0.125*log2e, split hi/lo, [bh][n][d].
//  K fragment-major: (bh*64+kt)*2048 + (kc*2+j)*512 + lane*8 + e
//  V fragment-major: (bh*64+kt)*2048 + j2*512 + lane*8 + e  (V^T frags)
// ---------------------------------------------------------------------------
__global__ __launch_bounds__(256) void k_qkv(
    const u16* __restrict__ xh, const u16* __restrict__ xl,
    const u16* __restrict__ wh, const u16* __restrict__ wl,
    u16* __restrict__ qh, u16* __restrict__ ql,
    u16* __restrict__ kf, u16* __restrict__ vf)
{
  __shared__ __align__(16) u16 BhL[64 * 256];   // 32 KB, swizzled
  __shared__ __align__(16) u16 BlL[64 * 256];   // 32 KB

  const int tid = threadIdx.x;
  const int w = tid >> 6, lane = tid & 63;
  const int ln = lane & 15, hb = lane >> 4;
  const int colb = blockIdx.x * 64;

  // ---- stage B (hi+lo) into LDS, reg-batched, coalesced ----
  {
    short8 sb[16];
#pragma unroll
    for (int it = 0; it < 8; ++it) {
      const int c = it * 8 + (tid >> 5), k8 = tid & 31;
      sb[it]     = *(const short8*)&wh[(colb + c) * 256 + k8 * 8];
      sb[8 + it] = *(const short8*)&wl[(colb + c) * 256 + k8 * 8];
    }
#pragma unroll
    for (int it = 0; it < 8; ++it) {
      const int c = it * 8 + (tid >> 5), k8 = tid & 31;
      const int le = c * 256 + ((k8 * 8) ^ ((c & 7) << 3));
      *(short8*)&BhL[le] = sb[it];
      *(short8*)&BlL[le] = sb[8 + it];
    }
  }
  __syncthreads();

#pragma unroll
  for (int st = 0; st < 2; ++st) {
    const int mtile = blockIdx.y * 2 + st;
    const int arow = mtile * 64 + w * 16 + ln;

    // ---- all 16 A-fragment loads issued upfront (in flight together) ----
    short8 a_h8[8], a_l8[8];
#pragma unroll
    for (int ks = 0; ks < 8; ++ks) {
      a_h8[ks] = *(const short8*)&xh[arow * 256 + ks * 32 + hb * 8];
      a_l8[ks] = *(const short8*)&xl[arow * 256 + ks * 32 + hb * 8];
    }

    f32x4 acc[4] = {};
#pragma unroll
    for (int ks = 0; ks < 8; ++ks) {
      const int k0 = ks * 32 + hb * 8;
#pragma unroll
      for (int j = 0; j < 4; ++j) {
        const int c = j * 16 + ln;
        const int le = c * 256 + (k0 ^ ((c & 7) << 3));
        const short8 b_h = *(const short8*)&BhL[le];
        const short8 b_l = *(const short8*)&BlL[le];
        acc[j] = MFMA16(a_h8[ks], b_h, acc[j]);
        acc[j] = MFMA16(a_l8[ks], b_h, acc[j]);
        acc[j] = MFMA16(a_h8[ks], b_l, acc[j]);
      }
    }

    // ---- epilogue (layouts identical to R8) ----
    const int mbase = mtile * 64 + w * 16 + hb * 4;
#pragma unroll
    for (int j = 0; j < 4; ++j) {
      const int c = colb + j * 16 + ln;
      const int which = c >> 8;        // 0=q 1=k 2=v
      const int hd = c & 255;
      const int hh = hd >> 6, d = hd & 63;
#pragma unroll
      for (int r = 0; r < 4; ++r) {
        const int m = mbase + r;
        const int bb = m >> 11, nn = m & 2047;
        const int bh = bb * H_ + hh;
        float v = acc[j][r];
        if (which == 0) {
          const int off = (bh * N_ + nn) * DH_ + d;
          v *= (0.125f * LOG2E);                 // scale + exp2-domain fold
          split2(v, &qh[off], &ql[off]);
        } else if (which == 1) {
          const int ktile = nn >> 5, jj = (nn >> 4) & 1, lnn = nn & 15;
          const int kc = d >> 5, hbb = (d >> 3) & 3, e = d & 7;
          const int off = (bh * 64 + ktile) * 2048 + (kc * 2 + jj) * 512
                        + (hbb * 16 + lnn) * 8 + e;
          kf[off] = f2bf(v);
        } else {
          const int ktile = nn >> 5, hbb = (nn >> 3) & 3, e = nn & 7;
          const int j2 = d >> 4, lnn = d & 15;
          const int off = (bh * 64 + ktile) * 2048 + j2 * 512
                        + (hbb * 16 + lnn) * 8 + e;
          vf[off] = f2bf(v);
        }
      }
    }
  }
}

// ---------------------------------------------------------------------------
// Kernel 3: flash attention partials, KV-split=2. grid 1024:
// bid = qq*32 + bh*2 + half; 4 waves = 4 q-tiles of SAME head share K/V in
// LDS (dbuf, 1 barrier/iter, reg-staged issue-early/write-late). Each block
// covers kt in [half*32, half*32+32). Writes unnormalized O into
// Op0 (half=0) / Op1 (half=1) + per-row m,l into MP/LP.
// ---------------------------------------------------------------------------
__global__ __launch_bounds__(256) void k_attn(
    const u16* __restrict__ qhg, const u16* __restrict__ qlg,
    const u16* __restrict__ kfg, const u16* __restrict__ vfg,
    const u16* __restrict__ biasF,
    float* __restrict__ Op0, float* __restrict__ Op1,
    float* __restrict__ MP, float* __restrict__ LP)
{
  __shared__ __align__(16) u16 KL[2][2048];    // 8 KB  (32x64 bf16 tile)
  __shared__ __align__(16) u16 VL[2][2048];    // 8 KB  (V^T fragments)
  __shared__ __align__(16) u32 Pbuf[4][320];   // 5 KB, per-wave P exchange

  const int bid = blockIdx.x;
  const int half = bid & 1;
  const int bh = (bid >> 1) & 15;
  const int qq = bid >> 5;
  const int b = bh >> 2, h = bh & 3;
  const int kt0 = half * 32;

  const int tid = threadIdx.x;
  const int w = tid >> 6, lane = tid & 63;
  const int qt = qq * 4 + w;                   // this wave's q-tile [0,128)
  const int ln = lane & 15, hb = lane >> 4;

  // ---- Q fragments (pre-scaled by 0.125*log2e), hi/lo ----
  short8 qfh[2], qfl[2];
  {
    const int base = ((b * H_ + h) * N_ + qt * 16 + ln) * DH_;
    qfh[0] = *(const short8*)&qhg[base + hb * 8];
    qfh[1] = *(const short8*)&qhg[base + 32 + hb * 8];
    qfl[0] = *(const short8*)&qlg[base + hb * 8];
    qfl[1] = *(const short8*)&qlg[base + 32 + hb * 8];
  }

  const u16* Kt0 = kfg + (size_t)((b * H_ + h) * 64) * 2048;
  const u16* Vt0 = vfg + (size_t)((b * H_ + h) * 64) * 2048;
  const u16* Bt0 = biasF + (size_t)((b * 128 + qt) * 64) * 512;
  const int stoff = w * 512 + lane * 8;  // this thread's staging slot (16B)
  const int l8 = lane * 8;

  short8 ones;
#pragma unroll
  for (int i = 0; i < 8; ++i) ones[i] = (short)0x3F80;   // bf16 1.0

  f32x4 O[4] = {};
  f32x4 l_acc = {};
  float m_run = NEGINF;
  u32* Pw = &Pbuf[w][0];

  short8 kst, vst, bc, bn;

  // ---- prologue: stage tile kt0, load bias kt0 ----
  kst = *(const short8*)&Kt0[kt0 * 2048 + stoff];
  vst = *(const short8*)&Vt0[kt0 * 2048 + stoff];
  bc  = *(const short8*)&Bt0[kt0 * 512 + l8];
  *(short8*)&KL[0][stoff] = kst;
  *(short8*)&VL[0][stoff] = vst;
  __syncthreads();

  int cur = 0;
  for (int kt = 0; kt < 32; ++kt) {
    const int ktn = kt0 + ((kt + 1) & 31);

    // ---- issue next-tile loads early (hide HBM/L2 latency under compute) --
    kst = *(const short8*)&Kt0[ktn * 2048 + stoff];
    vst = *(const short8*)&Vt0[ktn * 2048 + stoff];
    bn  = *(const short8*)&Bt0[ktn * 512 + l8];

    // ---- swapped QK^T from LDS: dots[j] lane(hb,ln)=S[k=j*16+hb*4+r][q=ln]
    f32x4 dots[2] = {};
    __builtin_amdgcn_s_setprio(1);
#pragma unroll
    for (int kc = 0; kc < 2; ++kc)
#pragma unroll
      for (int j = 0; j < 2; ++j) {
        const short8 kfr = *(const short8*)&KL[cur][(kc * 2 + j) * 512 + l8];
        dots[j] = MFMA16(kfr, qfh[kc], dots[j]);
        dots[j] = MFMA16(kfr, qfl[kc], dots[j]);
      }
    __builtin_amdgcn_s_setprio(0);

    // ---- bias add (fp16 regs from last iter) ----
    float lg[2][4];
#pragma unroll
    for (int j = 0; j < 2; ++j)
#pragma unroll
      for (int r = 0; r < 4; ++r) {
        const float bv = (float)__builtin_bit_cast(_Float16, (u16)bc[j * 4 + r]);
        lg[j][r] = dots[j][r] + bv;
      }

    // ---- per-lane online softmax (q=ln), defer-max THR=8 ----
    float pmax = fmaxf(fmaxf(fmaxf(lg[0][0], lg[0][1]), fmaxf(lg[0][2], lg[0][3])),
                       fmaxf(fmaxf(lg[1][0], lg[1][1]), fmaxf(lg[1][2], lg[1][3])));
    pmax = fmaxf(pmax, __shfl_xor(pmax, 16));
    pmax = fmaxf(pmax, __shfl_xor(pmax, 32));
    if (__any(pmax > m_run + DEFER_THR)) {
      const float mn = fmaxf(m_run, pmax);
      const float fac = exp2f(m_run - mn);
      m_run = mn;
#pragma unroll
      for (int r = 0; r < 4; ++r) {
        const float fr = bpermf(hb * 4 + r, fac);
        O[0][r] *= fr; O[1][r] *= fr; O[2][r] *= fr; O[3][r] *= fr;
        l_acc[r] *= fr;
      }
    }
    float p[2][4];
#pragma unroll
    for (int j = 0; j < 2; ++j)
#pragma unroll
      for (int r = 0; r < 4; ++r)
        p[j][r] = exp2f(lg[j][r] - m_run);

    // ---- pack bf16 + exchange to A-fragment via per-wave LDS ----
    {
      uint2 w0, w1;
      w0.x = cvtpk(p[0][0], p[0][1]); w0.y = cvtpk(p[0][2], p[0][3]);
      w1.x = cvtpk(p[1][0], p[1][1]); w1.y = cvtpk(p[1][2], p[1][3]);
      *(uint2*)&Pw[ln * 20 + hb * 2]     = w0;
      *(uint2*)&Pw[ln * 20 + 8 + hb * 2] = w1;
    }
    const short8 pf = *(const short8*)&Pw[ln * 20 + hb * 4];

    // ---- PV + row-sum via ones-MFMA (V frags from LDS) ----
    __builtin_amdgcn_s_setprio(1);
#pragma unroll
    for (int j2 = 0; j2 < 4; ++j2) {
      const short8 vfr = *(const short8*)&VL[cur][j2 * 512 + l8];
      O[j2] = MFMA16(pf, vfr, O[j2]);
    }
    l_acc = MFMA16(pf, ones, l_acc);
    __builtin_amdgcn_s_setprio(0);

    // ---- write staged tile into the other buffer (late write, T14) ----
    *(short8*)&KL[cur ^ 1][stoff] = kst;
    *(short8*)&VL[cur ^ 1][stoff] = vst;
    __syncthreads();
    bc = bn;
    cur ^= 1;
  }

  // ---- epilogue: write unnormalized partial O + per-row m,l ----
  const int gg = (b * H_ + h) * 128 + qt;          // [0, 2048)
  const int g  = gg * 2 + half;                    // MP/LP index
  float* Opg = (half ? Op1 : Op0) + (size_t)gg * 1024;
#pragma unroll
  for (int j2 = 0; j2 < 4; ++j2)
#pragma unroll
    for (int r = 0; r < 4; ++r)
      Opg[(hb * 4 + r) * 64 + j2 * 16 + ln] = O[j2][r];
  if (lane < 16) MP[g * 16 + lane] = m_run;       // hb=0, q=ln
  if (ln == 0) {
#pragma unroll
    for (int r = 0; r < 4; ++r) LP[g * 16 + hb * 4 + r] = l_acc[r];
  }
}

// ---------------------------------------------------------------------------
// Kernel 3b: combine the two kv-halves, normalize, write split-bf16 attn-out.
// grid 1024 x 256; thread -> (row, 8 cols).
// ---------------------------------------------------------------------------
__global__ __launch_bounds__(256) void k_comb(
    const float* __restrict__ Op0, const float* __restrict__ Op1,
    const float* __restrict__ MP, const float* __restrict__ LP,
    u16* __restrict__ ah, u16* __restrict__ al)
{
  const int i = blockIdx.x * 256 + threadIdx.x;   // [0, 262144)
  const int row = i >> 5, cg = i & 31;
  const int c0 = cg * 8, h = c0 >> 6, d0 = c0 & 63;
  const int b = row >> 11, nn = row & 2047, qt = nn >> 4, q = nn & 15;
  const int gg = (b * H_ + h) * 128 + qt;
  const int g0 = gg * 2;

  const float m1 = MP[g0 * 16 + q],       m2 = MP[(g0 + 1) * 16 + q];
  const float l1 = LP[g0 * 16 + q],       l2 = LP[(g0 + 1) * 16 + q];
  const float mm = fmaxf(m1, m2);
  const float f1 = exp2f(m1 - mm), f2 = exp2f(m2 - mm);
  const float inv = 1.0f / (l1 * f1 + l2 * f2);

  const float* p1 = Op0 + (size_t)gg * 1024 + q * 64 + d0;
  const float* p2 = Op1 + (size_t)gg * 1024 + q * 64 + d0;
  const f32x4 a1 = *(const f32x4*)p1, b1 = *(const f32x4*)(p1 + 4);
  const f32x4 a2 = *(const f32x4*)p2, b2 = *(const f32x4*)(p2 + 4);

  u16v8 hh, ll;
#pragma unroll
  for (int e = 0; e < 4; ++e) {
    const float v = (a1[e] * f1 + a2[e] * f2) * inv;
    split2(v, &hh.v[e], &ll.v[e]);
  }
#pragma unroll
  for (int e = 0; e < 4; ++e) {
    const float v = (b1[e] * f1 + b2[e] * f2) * inv;
    split2(v, &hh.v[e + 4], &ll.v[e + 4]);
  }
  *(u16v8*)&ah[row * DIMX + c0] = hh;
  *(u16v8*)&al[row * DIMX + c0] = ll;
}

// ---------------------------------------------------------------------------
// Kernel 4: out = aout @ Wout + b_out, LDS-staged. M=8192, N=256, K=256.
// grid (4, 64): colb = bx*64; 2 M-subtiles per block; B hi+lo in 64KB LDS.
// ---------------------------------------------------------------------------
__global__ __launch_bounds__(256) void k_out(
    const u16* __restrict__ ahg, const u16* __restrict__ alg,
    const u16* __restrict__ wh, const u16* __restrict__ wl,
    const float* __restrict__ bout, float* __restrict__ out)
{
  __shared__ __align__(16) u16 BhL[64 * 256];   // 32 KB, swizzled
  __shared__ __align__(16) u16 BlL[64 * 256];   // 32 KB

  const int tid = threadIdx.x;
  const int w = tid >> 6, lane = tid & 63;
  const int ln = lane & 15, hb = lane >> 4;
  const int colb = blockIdx.x * 64;

  // ---- stage B (hi+lo) into LDS ----
  {
    short8 sb[16];
#pragma unroll
    for (int it = 0; it < 8; ++it) {
      const int c = it * 8 + (tid >> 5), k8 = tid & 31;
      sb[it]     = *(const short8*)&wh[(colb + c) * 256 + k8 * 8];
      sb[8 + it] = *(const short8*)&wl[(colb + c) * 256 + k8 * 8];
    }
#pragma unroll
    for (int it = 0; it < 8; ++it) {
      const int c = it * 8 + (tid >> 5), k8 = tid & 31;
      const int le = c * 256 + ((k8 * 8) ^ ((c & 7) << 3));
      *(short8*)&BhL[le] = sb[it];
      *(short8*)&BlL[le] = sb[8 + it];
    }
  }
  __syncthreads();

#pragma unroll
  for (int st = 0; st < 2; ++st) {
    const int mtile = blockIdx.y * 2 + st;
    const int arow = mtile * 64 + w * 16 + ln;

    short8 a_h8[8], a_l8[8];
#pragma unroll
    for (int ks = 0; ks < 8; ++ks) {
      a_h8[ks] = *(const short8*)&ahg[arow * 256 + ks * 32 + hb * 8];
      a_l8[ks] = *(const short8*)&alg[arow * 256 + ks * 32 + hb * 8];
    }

    f32x4 acc[4] = {};
#pragma unroll
    for (int ks = 0; ks < 8; ++ks) {
      const int k0 = ks * 32 + hb * 8;
#pragma unroll
      for (int j = 0; j < 4; ++j) {
        const int c = j * 16 + ln;
        const int le = c * 256 + (k0 ^ ((c & 7) << 3));
        const short8 b_h = *(const short8*)&BhL[le];
        const short8 b_l = *(const short8*)&BlL[le];
        acc[j] = MFMA16(a_h8[ks], b_h, acc[j]);
        acc[j] = MFMA16(a_l8[ks], b_h, acc[j]);
        acc[j] = MFMA16(a_h8[ks], b_l, acc[j]);
      }
    }

    const int mbase = mtile * 64 + w * 16 + hb * 4;
#pragma unroll
    for (int j = 0; j < 4; ++j) {
      const int c = colb + j * 16 + ln;
      const float bb = bout[c];
#pragma unroll
      for (int r = 0; r < 4; ++r)
        out[(mbase + r) * 256 + c] = acc[j][r] + bb;
    }
  }
}

// ---------------------------------------------------------------------------
extern "C" void kernel_launch(void* const* d_in, const int* in_sizes, int n_in,
                              void* d_out, int out_size, void* d_ws, size_t ws_size,
                              hipStream_t stream)
{
  (void)in_sizes; (void)n_in; (void)out_size; (void)ws_size;
  const float* x    = (const float*)d_in[0];
  const int*   mask = (const int*)d_in[1];
  const float* spat = (const float*)d_in[2];
  const float* wq   = (const float*)d_in[3];
  const float* wo   = (const float*)d_in[4];
  const float* bout = (const float*)d_in[5];
  float* out = (float*)d_out;

  char* ws = (char*)d_ws;
  size_t o = 0;
  auto alloc = [&](size_t bytes) -> char* {
    char* p = ws + o;
    o += (bytes + 255) & ~(size_t)255;
    return p;
  };
  u16* xh  = (u16*)alloc((size_t)M_ * 256 * 2);   // 4 MB  \ Op0 alias (8 MB)
  u16* xl  = (u16*)alloc((size_t)M_ * 256 * 2);   // 4 MB  /
  u16* wqh = (u16*)alloc((size_t)768 * 256 * 2);  // 384KB -> MP alias (256KB)
  u16* wql = (u16*)alloc((size_t)768 * 256 * 2);  // 384KB -> LP alias (256KB)
  u16* woh = (u16*)alloc((size_t)256 * 256 * 2);
  u16* wol = (u16*)alloc((size_t)256 * 256 * 2);
  u16* qh  = (u16*)alloc((size_t)16 * N_ * DH_ * 2);
  u16* ql  = (u16*)alloc((size_t)16 * N_ * DH_ * 2);
  u16* kf  = (u16*)alloc((size_t)16 * N_ * DH_ * 2);
  u16* vf  = (u16*)alloc((size_t)16 * N_ * DH_ * 2);
  u16* ah  = (u16*)alloc((size_t)M_ * 256 * 2);
  u16* al  = (u16*)alloc((size_t)M_ * 256 * 2);
  u16* biasF = (u16*)alloc((size_t)4 * 128 * 64 * 512 * 2);  // 33.5 MB fp16

  // Safe scratch aliases (sizes verified):
  //  Op0 (2048*1024*4 = 8,388,608 B) <- xh+xl (4,194,304*2, contiguous,
  //      dead after k_qkv, never read later)
  //  Op1 (8,388,608 B) <- d_out (8192*256*4 = 8,388,608 B, fully
  //      overwritten by k_out at the end -> deterministic)
  //  MP/LP (4096*16*4 = 262,144 B each) <- wqh / wql (393,216 B each,
  //      dead after k_qkv, never read later)
  float* Op0 = (float*)xh;
  float* Op1 = out;
  float* MP  = (float*)wqh;
  float* LP  = (float*)wql;

  hipLaunchKernelGGL(k_prep, dim3(11264), dim3(256), 0, stream,
                     mask, spat, x, wq, wo, biasF,
                     xh, xl, wqh, wql, woh, wol);
  hipLaunchKernelGGL(k_qkv, dim3(12, 64), dim3(256), 0, stream,
                     xh, xl, wqh, wql, qh, ql, kf, vf);
  hipLaunchKernelGGL(k_attn, dim3(1024), dim3(256), 0, stream,
                     qh, ql, kf, vf, biasF, Op0, Op1, MP, LP);
  hipLaunchKernelGGL(k_comb, dim3(1024), dim3(256), 0, stream,
                     Op0, Op1, MP, LP, ah, al);
  hipLaunchKernelGGL(k_out, dim3(4, 64), dim3(256), 0, stream,
                     ah, al, woh, wol, bout, out);
}